// Round 3
// baseline (768.863 us; speedup 1.0000x reference)
//
#include <hip/hip_runtime.h>

// AliasFreeActivation fused kernel, v3: plane-pair (float2) + rolling register
// windows with static ring indexing (forces reg-residency; v2's VGPR=68 showed
// the compiler demoted r[21]/acc[26]/rr[36] to LDS re-reads).
//
// Math (identical to v1/v2, both passed):
//   upH -> (upW + leaky + downW fused) -> downH, crop folded in.
//   hi[l] = sum_{t=0..5} x[m0+t]*up[c0-4t], m0=(l+5)>>2, c0=20+((l+1)&3)
//   out[o] = sum_k hl[2o+k]*dn[11-k]
//
// v3 changes:
//  - P2: 6-tap rolling window w[(rel+t)%6], one LDS read per 4 j-steps (21 total).
//    Extra __syncthreads() before t2 writeback keeps the LDS overlay safe now
//    that tH reads are spread through the loop.
//  - P3: 16-row ring with 2-output prefetch lookahead (32 VGPR vs 72).
//  - leaky_relu = max(h, 0.2h) (2 ops).
//  - __launch_bounds__(256,2): VGPR cap 256 (occupancy stays LDS-bound at
//    3 blocks/CU), so the allocator won't demote arrays.

typedef float v2f __attribute__((ext_vector_type(2)));

static __device__ __forceinline__ v2f vsplat(float s) { v2f v; v.x = s; v.y = s; return v; }

__global__ __launch_bounds__(256, 2)
void afa_kernel(const float* __restrict__ x,
                const float* __restrict__ upf,
                const float* __restrict__ dnf,
                float* __restrict__ out)
{
    // Overlay: tH rows stride 35 (first 3990 elems), later t2 rows stride 53.
    __shared__ v2f buf[114 * 53];   // 48336 bytes

    const int tid = threadIdx.x;
    const size_t q0 = (size_t)blockIdx.x * 2;
    const float* __restrict__ xp0 = x + q0 * 1296;
    const float* __restrict__ xp1 = xp0 + 1296;
    float* __restrict__ op0 = out + q0 * 2704;
    float* __restrict__ op1 = op0 + 2704;

    // filters -> uniform registers (SGPRs)
    float up[24];
#pragma unroll
    for (int i = 0; i < 24; ++i) up[i] = upf[i];
    float dn[12];
#pragma unroll
    for (int i = 0; i < 12; ++i) dn[i] = dnf[i];

    // ---------------- Pass 1: upsample along H ----------------
    if (tid < 204) {
        const int s  = tid / 34;
        const int mw = tid % 34 + 1;

        v2f xr[11];                        // x rows 5s+1 .. 5s+11 (clamped)
#pragma unroll
        for (int jj = 0; jj < 11; ++jj) {
            int row = 5 * s + 1 + jj;
            row = row > 35 ? 35 : row;     // clamp; clamped values never used
            xr[jj].x = xp0[row * 36 + mw];
            xr[jj].y = xp1[row * 36 + mw];
        }
        const int lh0  = 20 * s;
        const int jmax = (s == 5) ? 14 : 20;
#pragma unroll
        for (int j = 0; j < 20; ++j) {
            if (j < jmax) {
                const int rel = ((j + 5) >> 2) - 1;   // compile-time
                const int c0  = 20 + ((j + 1) & 3);   // compile-time
                v2f acc = vsplat(0.f);
#pragma unroll
                for (int t = 0; t < 6; ++t)
                    acc = __builtin_elementwise_fma(xr[rel + t], vsplat(up[c0 - 4 * t]), acc);
                buf[(lh0 + j) * 35 + (mw - 1)] = acc;  // tH region
            }
        }
    }
    __syncthreads();

    // ---------- Pass 2: upW + leaky + downW, rolling 6-tap window ----------
    const int  lh   = tid % 114;
    const int  p    = tid / 114;           // 0/1 for tid<228
    const bool act2 = tid < 228;
    v2f acc[26];                           // lives across the overlay barrier
    if (act2) {
        const int base = lh * 35 + 13 * p;
        v2f w[6];
#pragma unroll
        for (int t = 0; t < 6; ++t) w[t] = buf[base + t];
#pragma unroll
        for (int o = 0; o < 26; ++o) acc[o] = vsplat(0.f);

#pragma unroll
        for (int j = 0; j < 62; ++j) {     // lw = 52p + j
            const int rel = ((j + 5) >> 2) - 1;    // 0..15, compile-time
            const int c0  = 20 + ((j + 1) & 3);
            v2f h = vsplat(0.f);
#pragma unroll
            for (int t = 0; t < 6; ++t)
                h = __builtin_elementwise_fma(w[(rel + t) % 6], vsplat(up[c0 - 4 * t]), h);
            // leaky_relu: max(h, 0.2h)
            h = __builtin_elementwise_max(h, h * vsplat(0.2f));
#pragma unroll
            for (int k = 0; k < 12; ++k) { // scatter into down-W accumulators
                const int jk = j - k;
                if (jk >= 0 && (jk & 1) == 0 && (jk >> 1) < 26)
                    acc[jk >> 1] = __builtin_elementwise_fma(h, vsplat(dn[11 - k]), acc[jk >> 1]);
            }
            // window advance: rel increments entering j+1 when (j&3)==2;
            // new top element r[rel+6] replaces r[rel] (slot rel%6, just consumed)
            if ((j & 3) == 2)
                w[rel % 6] = buf[base + rel + 6];   // max index base+20
        }
    }
    __syncthreads();   // all tH reads complete before any t2 write (overlay)

    if (act2) {
#pragma unroll
        for (int o = 0; o < 26; ++o)
            buf[lh * 53 + 26 * p + o] = acc[o];    // t2 region
    }
    __syncthreads();

    // ---------------- Pass 3: downsample along H + store (16-row ring) ----------------
    if (tid < 208) {
        const int ow    = tid % 52;
        const int s     = tid / 52;
        const int rbase = 26 * s;          // t2 rows rbase .. rbase+35 at col ow

        v2f w[16];
#pragma unroll
        for (int mm = 0; mm < 14; ++mm)    // preload rows 0..13 (out0 + lookahead)
            w[mm] = buf[(rbase + mm) * 53 + ow];

#pragma unroll
        for (int j = 0; j < 13; ++j) {
            // prefetch rows 2j+14, 2j+15 (overwrite rows 2j-2, 2j-1: already consumed)
            if (2 * j + 14 < 36) w[(2 * j + 14) & 15] = buf[(rbase + 2 * j + 14) * 53 + ow];
            if (2 * j + 15 < 36) w[(2 * j + 15) & 15] = buf[(rbase + 2 * j + 15) * 53 + ow];
            v2f a = vsplat(0.f);
#pragma unroll
            for (int k = 0; k < 12; ++k)
                a = __builtin_elementwise_fma(w[(2 * j + k) & 15], vsplat(dn[11 - k]), a);
            const int o = (13 * s + j) * 52 + ow;
            op0[o] = a.x;
            op1[o] = a.y;
        }
    }
}

extern "C" void kernel_launch(void* const* d_in, const int* in_sizes, int n_in,
                              void* d_out, int out_size, void* d_ws, size_t ws_size,
                              hipStream_t stream)
{
    const float* x  = (const float*)d_in[0];   // (16,512,36,36)
    const float* up = (const float*)d_in[1];   // (24,)
    const float* dn = (const float*)d_in[2];   // (12,)
    float* out = (float*)d_out;                // (16,512,52,52)

    const int pairs = 16 * 512 / 2;            // 4096 blocks, one plane-pair each
    afa_kernel<<<dim3(pairs), dim3(256), 0, stream>>>(x, up, dn, out);
}

// Round 4
// 143.604 us; speedup vs baseline: 5.3541x; 5.3541x over previous
//
#include <hip/hip_runtime.h>

// AliasFreeActivation fused kernel, v4.
// Skeleton = v2 (passed, 60 µs). Change: pass-2/pass-3 tap windows are NAMED
// registers rotated via macro argument renaming (no arrays, no modulo), so
// they cannot be demoted to scratch (v3 lesson) and LDS re-reads drop 18x
// (v2 was LDS-BW-bound: ~372 ds_read_b64/thread in pass 2 -> 21).
//
// Math (identical to v1/v2/v3, all passed correctness):
//   upH -> (upW + leaky + downW fused) -> downH, crop folded in.
//   hi[l] = sum_{t=0..5} x[m0+t]*up[c0-4t], m0=(l+5)>>2, c0=20+((l+1)&3)
//   out[o] = sum_k hl[2o+k]*dn[11-k]
// Plane-pair per block as float2 (v_pk_fma_f32). LDS overlay tH/t2 with a
// barrier between last tH read and first t2 write. 48336 B -> 3 blocks/CU.

typedef float v2f __attribute__((ext_vector_type(2)));

static __device__ __forceinline__ v2f vsplat(float s) { v2f v; v.x = s; v.y = s; return v; }
#define VFMA(A, S, C) __builtin_elementwise_fma((A), vsplat(S), (C))

// ---- pass 2: one upsampled sample j from 6 named taps, leaky, scatter ----
// taps A..F = tH[rel..rel+5], coeff up[c0-4t], c0 = 20+((j+1)&3)
#define SCATTER(J, hv)                                                        \
    _Pragma("unroll")                                                         \
    for (int k = (J) & 1; k <= 11; k += 2) {                                  \
        if ((J) - k >= 0 && (((J) - k) >> 1) < 26)                            \
            acc[((J) - k) >> 1] = VFMA(hv, dn[11 - k], acc[((J) - k) >> 1]);  \
    }

#define DO_J(J, A, B, C, D, E, F)                                             \
    do {                                                                      \
        const int q_ = ((J) + 1) & 3;                                         \
        v2f h_ = (A) * vsplat(up[20 + q_]);                                   \
        h_ = VFMA((B), up[16 + q_], h_);                                      \
        h_ = VFMA((C), up[12 + q_], h_);                                      \
        h_ = VFMA((D), up[8 + q_], h_);                                       \
        h_ = VFMA((E), up[4 + q_], h_);                                       \
        h_ = VFMA((F), up[q_], h_);                                           \
        h_ = __builtin_elementwise_max(h_, h_ * vsplat(0.2f));                \
        SCATTER(J, h_);                                                       \
    } while (0)

// Entering GROUP(G): regs hold taps G-1..G+4 in (T0..T5). Load tap G+5 into
// T0 (tap G-1 is dead), giving taps G..G+5 in (T1..T5,T0); emit 4 samples.
#define GROUP(G, T0, T1, T2, T3, T4, T5)                                      \
    do {                                                                      \
        T0 = wbase[(G) + 5];                                                  \
        DO_J(4 * (G) - 1, T1, T2, T3, T4, T5, T0);                            \
        DO_J(4 * (G), T1, T2, T3, T4, T5, T0);                                \
        DO_J(4 * (G) + 1, T1, T2, T3, T4, T5, T0);                            \
        DO_J(4 * (G) + 2, T1, T2, T3, T4, T5, T0);                            \
    } while (0)

#define GROUP_TAIL(T0, T1, T2, T3, T4, T5)                                    \
    do {                                                                      \
        T0 = wbase[20];                                                       \
        DO_J(59, T1, T2, T3, T4, T5, T0);                                     \
        DO_J(60, T1, T2, T3, T4, T5, T0);                                     \
        DO_J(61, T1, T2, T3, T4, T5, T0);                                     \
    } while (0)

// ---- pass 3: output row J from 12 named row-regs (rows 2J..2J+11) ----
#define P3LD(RA, RB, M)                                                       \
    RA = p3b[(M)*53];                                                         \
    RB = p3b[((M) + 1) * 53];

#define P3OUT(J, A, B, C, D, E, F, G, H, I, JJ, K, L)                         \
    do {                                                                      \
        v2f a_ = (A) * vsplat(dn[11]);                                        \
        a_ = VFMA((B), dn[10], a_);                                           \
        a_ = VFMA((C), dn[9], a_);                                            \
        a_ = VFMA((D), dn[8], a_);                                            \
        a_ = VFMA((E), dn[7], a_);                                            \
        a_ = VFMA((F), dn[6], a_);                                            \
        a_ = VFMA((G), dn[5], a_);                                            \
        a_ = VFMA((H), dn[4], a_);                                            \
        a_ = VFMA((I), dn[3], a_);                                            \
        a_ = VFMA((JJ), dn[2], a_);                                           \
        a_ = VFMA((K), dn[1], a_);                                            \
        a_ = VFMA((L), dn[0], a_);                                            \
        const int o_ = (13 * s + (J)) * 52 + ow;                              \
        op0[o_] = a_.x;                                                       \
        op1[o_] = a_.y;                                                       \
    } while (0)

__global__ __launch_bounds__(256, 3)
void afa_kernel(const float* __restrict__ x,
                const float* __restrict__ upf,
                const float* __restrict__ dnf,
                float* __restrict__ out)
{
    // Overlay: tH rows stride 35 (first 3990 elems), later t2 rows stride 53.
    __shared__ v2f buf[114 * 53];   // 48336 bytes

    const int tid = threadIdx.x;
    const size_t q0 = (size_t)blockIdx.x * 2;
    const float* __restrict__ xp0 = x + q0 * 1296;
    const float* __restrict__ xp1 = xp0 + 1296;
    float* __restrict__ op0 = out + q0 * 2704;
    float* __restrict__ op1 = op0 + 2704;

    // filters -> uniform registers (SGPRs via scalar loads)
    float up[24];
#pragma unroll
    for (int i = 0; i < 24; ++i) up[i] = upf[i];
    float dn[12];
#pragma unroll
    for (int i = 0; i < 12; ++i) dn[i] = dnf[i];

    // ---------------- Pass 1: upsample along H ----------------
    if (tid < 204) {
        const int s1 = tid / 34;
        const int mw = tid % 34 + 1;

        v2f xr[11];                         // x rows 5s+1 .. 5s+11 (clamped)
#pragma unroll
        for (int jj = 0; jj < 11; ++jj) {
            int row = 5 * s1 + 1 + jj;
            row = row > 35 ? 35 : row;      // clamp; clamped values never used
            xr[jj].x = xp0[row * 36 + mw];
            xr[jj].y = xp1[row * 36 + mw];
        }
        const int lh0  = 20 * s1;
        const int jmax = (s1 == 5) ? 14 : 20;
#pragma unroll
        for (int j = 0; j < 20; ++j) {
            if (j < jmax) {
                const int rel = ((j + 5) >> 2) - 1;   // compile-time
                const int c0  = 20 + ((j + 1) & 3);   // compile-time
                v2f a = vsplat(0.f);
#pragma unroll
                for (int t = 0; t < 6; ++t)
                    a = VFMA(xr[rel + t], up[c0 - 4 * t], a);
                buf[(lh0 + j) * 35 + (mw - 1)] = a;   // tH region
            }
        }
    }
    __syncthreads();

    // ---------- Pass 2: upW + leaky + downW, named-reg rolling window ----------
    const int  lh   = tid % 114;
    const int  p    = tid / 114;            // 0/1 for tid<228
    const bool act2 = tid < 228;
    v2f acc[26];                            // static-index only (v2: stayed in regs)
    if (act2) {
        const v2f* __restrict__ wbase = &buf[lh * 35 + 13 * p];
        v2f w0 = wbase[0], w1 = wbase[1], w2 = wbase[2],
            w3 = wbase[3], w4 = wbase[4], w5 = wbase[5];
#pragma unroll
        for (int o = 0; o < 26; ++o) acc[o] = vsplat(0.f);

        DO_J(0, w0, w1, w2, w3, w4, w5);    // rel=0: taps 0..5
        DO_J(1, w0, w1, w2, w3, w4, w5);
        DO_J(2, w0, w1, w2, w3, w4, w5);
        GROUP(1,  w0, w1, w2, w3, w4, w5);  // -> taps 1..6 in (w1..w5,w0)
        GROUP(2,  w1, w2, w3, w4, w5, w0);
        GROUP(3,  w2, w3, w4, w5, w0, w1);
        GROUP(4,  w3, w4, w5, w0, w1, w2);
        GROUP(5,  w4, w5, w0, w1, w2, w3);
        GROUP(6,  w5, w0, w1, w2, w3, w4);
        GROUP(7,  w0, w1, w2, w3, w4, w5);
        GROUP(8,  w1, w2, w3, w4, w5, w0);
        GROUP(9,  w2, w3, w4, w5, w0, w1);
        GROUP(10, w3, w4, w5, w0, w1, w2);
        GROUP(11, w4, w5, w0, w1, w2, w3);
        GROUP(12, w5, w0, w1, w2, w3, w4);
        GROUP(13, w0, w1, w2, w3, w4, w5);
        GROUP(14, w1, w2, w3, w4, w5, w0);
        GROUP_TAIL(w2, w3, w4, w5, w0, w1); // tap 20; j=59..61
    }
    __syncthreads();   // all tH reads complete before any t2 write (overlay)

    if (act2) {
        v2f* __restrict__ tw = &buf[lh * 53 + 26 * p];
#pragma unroll
        for (int o = 0; o < 26; ++o) tw[o] = acc[o];  // t2 region
    }
    __syncthreads();

    // ---------------- Pass 3: downsample along H + store ----------------
    if (tid < 208) {
        const int ow = tid % 52;
        const int s  = tid / 52;
        const v2f* __restrict__ p3b = &buf[(26 * s) * 53 + ow];  // rows via M*53

        v2f r0, r1, r2, r3, r4, r5, r6, r7, r8, r9, r10, r11;
        P3LD(r0, r1, 0)  P3LD(r2, r3, 2)  P3LD(r4, r5, 4)
        P3LD(r6, r7, 6)  P3LD(r8, r9, 8)  P3LD(r10, r11, 10)

        P3OUT(0, r0, r1, r2, r3, r4, r5, r6, r7, r8, r9, r10, r11);
        P3LD(r0, r1, 12)
        P3OUT(1, r2, r3, r4, r5, r6, r7, r8, r9, r10, r11, r0, r1);
        P3LD(r2, r3, 14)
        P3OUT(2, r4, r5, r6, r7, r8, r9, r10, r11, r0, r1, r2, r3);
        P3LD(r4, r5, 16)
        P3OUT(3, r6, r7, r8, r9, r10, r11, r0, r1, r2, r3, r4, r5);
        P3LD(r6, r7, 18)
        P3OUT(4, r8, r9, r10, r11, r0, r1, r2, r3, r4, r5, r6, r7);
        P3LD(r8, r9, 20)
        P3OUT(5, r10, r11, r0, r1, r2, r3, r4, r5, r6, r7, r8, r9);
        P3LD(r10, r11, 22)
        P3OUT(6, r0, r1, r2, r3, r4, r5, r6, r7, r8, r9, r10, r11);
        P3LD(r0, r1, 24)
        P3OUT(7, r2, r3, r4, r5, r6, r7, r8, r9, r10, r11, r0, r1);
        P3LD(r2, r3, 26)
        P3OUT(8, r4, r5, r6, r7, r8, r9, r10, r11, r0, r1, r2, r3);
        P3LD(r4, r5, 28)
        P3OUT(9, r6, r7, r8, r9, r10, r11, r0, r1, r2, r3, r4, r5);
        P3LD(r6, r7, 30)
        P3OUT(10, r8, r9, r10, r11, r0, r1, r2, r3, r4, r5, r6, r7);
        P3LD(r8, r9, 32)
        P3OUT(11, r10, r11, r0, r1, r2, r3, r4, r5, r6, r7, r8, r9);
        P3LD(r10, r11, 34)
        P3OUT(12, r0, r1, r2, r3, r4, r5, r6, r7, r8, r9, r10, r11);
    }
}

extern "C" void kernel_launch(void* const* d_in, const int* in_sizes, int n_in,
                              void* d_out, int out_size, void* d_ws, size_t ws_size,
                              hipStream_t stream)
{
    const float* x  = (const float*)d_in[0];   // (16,512,36,36)
    const float* up = (const float*)d_in[1];   // (24,)
    const float* dn = (const float*)d_in[2];   // (12,)
    float* out = (float*)d_out;                // (16,512,52,52)

    const int pairs = 16 * 512 / 2;            // 4096 blocks, one plane-pair each
    afa_kernel<<<dim3(pairs), dim3(256), 0, stream>>>(x, up, dn, out);
}